// Round 12
// baseline (534.238 us; speedup 1.0000x reference)
//
#include <hip/hip_runtime.h>

#define BATCH 8
#define NPTS  2048
#define KNN   20
#define M1    (BATCH * NPTS * KNN)   // 327680 rows for conv stages
#define M5    (BATCH * NPTS)         // 16384 rows for final projection
#define EPSBN 1e-5f
#define LDA   40                      // padded LDS k-stride (halfs): 2-way max aliasing

typedef unsigned short bf16_t;
typedef _Float16 half8 __attribute__((ext_vector_type(8)));
typedef _Float16 half4v __attribute__((ext_vector_type(4)));
typedef float    floatx4 __attribute__((ext_vector_type(4)));

__device__ __forceinline__ float bf2f(bf16_t u) {
    return __uint_as_float(((unsigned int)u) << 16);
}
__device__ __forceinline__ bf16_t f2bf(float f) {
    unsigned int u = __float_as_uint(f);
    return (bf16_t)((u + 0x7fffu + ((u >> 16) & 1u)) >> 16);
}
__device__ __forceinline__ float lrelu(float v) { return v >= 0.f ? v : 0.2f * v; }

// ---------------------------------------------------------------------------
// KNN v7 (unchanged).
// ---------------------------------------------------------------------------
#define DPPMAX(v, ctrl)                                                      \
    {                                                                        \
        unsigned int o_ = (unsigned int)__builtin_amdgcn_update_dpp(         \
            (int)(v), (int)(v), ctrl, 0xF, 0xF, false);                      \
        if (o_ > (v)) (v) = o_;                                              \
    }
#define SWZMAX32(v)                                                          \
    {                                                                        \
        unsigned int o_ = (unsigned int)__builtin_amdgcn_ds_swizzle(         \
            (int)(v), 0x401F);                                               \
        if (o_ > (v)) (v) = o_;                                              \
    }
#define GRPMAX32(v)                                                          \
    DPPMAX(v, 0xB1)  /* quad_perm(1,0,3,2): xor1  */                         \
    DPPMAX(v, 0x4E)  /* quad_perm(2,3,0,1): xor2  */                         \
    DPPMAX(v, 0x141) /* row_half_mirror:    xor7  */                         \
    DPPMAX(v, 0x140) /* row_mirror:         xor15 */                         \
    SWZMAX32(v)      /* ds_swizzle:         xor16 */

#define DIST_KEY(pm, idxv, kp)                                               \
    {                                                                        \
        float inner_ = __fadd_rn(__fadd_rn(__fmul_rn(xn0, (pm).x),           \
                                           __fmul_rn(xn1, (pm).y)),          \
                                 __fmul_rn(xn2, (pm).z));                    \
        float d_ = __fsub_rn(__fsub_rn(__fmul_rn(2.0f, inner_), xxn),        \
                             (pm).w);                                        \
        unsigned int s_ = ~__float_as_uint(d_);                              \
        kp = ((unsigned long long)s_ << 32) | (unsigned int)(idxv);          \
    }

#define INS3(kp)                                                             \
    {                                                                        \
        bool c1_ = (kp) > k1, c2_ = (kp) > k2, c3_ = (kp) > k3;              \
        k3 = c2_ ? k2 : (c3_ ? (kp) : k3);                                   \
        k2 = c1_ ? k1 : (c2_ ? (kp) : k2);                                   \
        k1 = c1_ ? (kp) : k1;                                                \
    }

__global__ __launch_bounds__(512, 8) void knn_kernel(const float* __restrict__ x,
                                                     int* __restrict__ idx)
{
    __shared__ float4 pts[NPTS];              // 32 KB
    int t = threadIdx.x;
    int b = blockIdx.x >> 7;                  // 128 blocks per batch
    int base = (blockIdx.x & 127) * 16;       // 16 points per block (2/wave)
    const float* xb = x + (size_t)b * 3 * NPTS;
    for (int i = t; i < NPTS; i += 512) {
        float a0 = xb[i], a1 = xb[NPTS + i], a2 = xb[2 * NPTS + i];
        float xx = __fadd_rn(__fadd_rn(__fmul_rn(a0, a0), __fmul_rn(a1, a1)),
                             __fmul_rn(a2, a2));
        pts[i] = make_float4(a0, a1, a2, xx);
    }
    __syncthreads();
    int w = t >> 6, lane = t & 63;
    int gl = lane & 31;                       // lane within 32-lane group
    int n = base + w * 2 + (lane >> 5);       // this group's point
    float4 pn = pts[n];
    float xn0 = pn.x, xn1 = pn.y, xn2 = pn.z, xxn = pn.w;
    unsigned long long k1 = 0ULL, k2 = 0ULL, k3 = 0ULL;  // 0 < any real key
    unsigned long long emask = 0ULL;          // extracted slots (j index, 64 bits)

    // ---- distance phase: 8 candidates per iteration (batched LDS loads) ----
    {
        const float4* pp = pts + gl;
        unsigned int idxv = 2047u - (unsigned int)gl;   // NPTS-1-m for m=gl
        for (int jo = 0; jo < 64; jo += 8) {
            float4 p0 = pp[0],   p1 = pp[32],  p2 = pp[64],  p3 = pp[96];
            float4 p4 = pp[128], p5 = pp[160], p6 = pp[192], p7 = pp[224];
            pp += 256;
            unsigned long long kp0, kp1, kp2, kp3, kp4, kp5, kp6, kp7;
            DIST_KEY(p0, idxv,        kp0);
            DIST_KEY(p1, idxv - 32u,  kp1);
            DIST_KEY(p2, idxv - 64u,  kp2);
            DIST_KEY(p3, idxv - 96u,  kp3);
            DIST_KEY(p4, idxv - 128u, kp4);
            DIST_KEY(p5, idxv - 160u, kp5);
            DIST_KEY(p6, idxv - 192u, kp6);
            DIST_KEY(p7, idxv - 224u, kp7);
            INS3(kp0);
            INS3(kp1);
            INS3(kp2);
            INS3(kp3);
            INS3(kp4);
            INS3(kp5);
            INS3(kp6);
            INS3(kp7);
            idxv -= 256u;
        }
    }

    int* op = idx + (size_t)(b * NPTS + n) * KNN;

    // ---- round 0: self-point (s=0xFFFFFFFF is the strict max key) ----
    if (gl == 0) op[0] = n;
    if ((n & 31) == gl) {                     // self always is owner's k1
        emask |= 1ULL << (n >> 5);
        k1 = k2; k2 = k3; k3 = 0ULL;          // 64 cands/lane -> k2,k3 valid
    }

    for (int r = 1; r < KNN; ++r) {
        unsigned int s1 = (unsigned int)(k1 >> 32);
        unsigned int sm = s1;
        GRPMAX32(sm)                          // global max distance-key
        unsigned int lm = (sm == s1) ? (unsigned int)k1 : 0u;
        GRPMAX32(lm)                          // max idxv among s==sm lanes
        int m_ex = 2047 - (int)(lm & 0x7FFu);
        if (gl == 0) op[r] = m_ex;
        if (r < KNN - 1 && (m_ex & 31) == gl) {   // owner lane updates top-3
            emask |= 1ULL << (m_ex >> 5);
            if (k2 != 0ULL) { k1 = k2; k2 = k3; k3 = 0ULL; }
            else {                             // rare: recompute survivors
                k1 = 0ULL; k2 = 0ULL; k3 = 0ULL;
                const float4* pr = pts + gl;
                unsigned int idr = 2047u - (unsigned int)gl;
                for (int j = 0; j < 64; ++j) {
                    if (!(emask & (1ULL << j))) {
                        float4 pm = pr[j * 32];
                        unsigned long long kr;
                        DIST_KEY(pm, idr - (unsigned int)(j * 32), kr);
                        INS3(kr);
                    }
                }
            }
        }
    }
}

// ---------------------------------------------------------------------------
// conv1 v2 — row-per-thread: 1280 blocks x 256 rows. Features in registers,
// W1 broadcast from LDS, 384 FMA/thread, coalesced uint4 bf16 stores, no
// mid-kernel barriers. Stats via 6x6 Gram (colsum = fsum.w, colsq = w^T G w):
// 27 register partials, wave shfl-reduce, 64-bucket atomics.
// ---------------------------------------------------------------------------
__global__ __launch_bounds__(256) void conv1_kernel(const float* __restrict__ x,
                                                    const int* __restrict__ idx,
                                                    const float* __restrict__ W1,
                                                    bf16_t* __restrict__ Y,
                                                    float* __restrict__ Gst)
{
    __shared__ float w[384];
    int t = threadIdx.x;
    for (int i = t; i < 384; i += 256) w[i] = W1[i];
    __syncthreads();
    int gr = blockIdx.x * 256 + t;
    int bn = gr / KNN;
    int j = idx[gr];
    int b = bn >> 11, n = bn & (NPTS - 1);
    const float* xb = x + (size_t)b * 3 * NPTS;
    float xi0 = xb[n], xi1 = xb[NPTS + n], xi2 = xb[2 * NPTS + n];
    float xj0 = xb[j], xj1 = xb[NPTS + j], xj2 = xb[2 * NPTS + j];
    float f0 = xj0 - xi0, f1 = xj1 - xi1, f2 = xj2 - xi2;
    float f3 = xi0, f4 = xi1, f5 = xi2;
    bf16_t* yrow = Y + (size_t)gr * 64;
#pragma unroll
    for (int c0 = 0; c0 < 64; c0 += 8) {
        unsigned int pk[4];
#pragma unroll
        for (int cc = 0; cc < 8; cc += 2) {
            const float* wc = &w[(c0 + cc) * 6];
            float ya = f0 * wc[0] + f1 * wc[1] + f2 * wc[2] +
                       f3 * wc[3] + f4 * wc[4] + f5 * wc[5];
            float yb = f0 * wc[6] + f1 * wc[7] + f2 * wc[8] +
                       f3 * wc[9] + f4 * wc[10] + f5 * wc[11];
            pk[cc >> 1] = (unsigned int)f2bf(ya) | ((unsigned int)f2bf(yb) << 16);
        }
        *(uint4*)(yrow + c0) = *(uint4*)pk;
    }
    float v[27];
    v[0] = f0; v[1] = f1; v[2] = f2; v[3] = f3; v[4] = f4; v[5] = f5;
    v[6]  = f0 * f0; v[7]  = f0 * f1; v[8]  = f0 * f2; v[9]  = f0 * f3;
    v[10] = f0 * f4; v[11] = f0 * f5;
    v[12] = f1 * f1; v[13] = f1 * f2; v[14] = f1 * f3; v[15] = f1 * f4;
    v[16] = f1 * f5;
    v[17] = f2 * f2; v[18] = f2 * f3; v[19] = f2 * f4; v[20] = f2 * f5;
    v[21] = f3 * f3; v[22] = f3 * f4; v[23] = f3 * f5;
    v[24] = f4 * f4; v[25] = f4 * f5;
    v[26] = f5 * f5;
#pragma unroll
    for (int k = 0; k < 27; ++k) {
        float s = v[k];
        s += __shfl_xor(s, 1);  s += __shfl_xor(s, 2);
        s += __shfl_xor(s, 4);  s += __shfl_xor(s, 8);
        s += __shfl_xor(s, 16); s += __shfl_xor(s, 32);
        v[k] = s;
    }
    if ((t & 63) == 0) {
        int bucket = (blockIdx.x * 4 + (t >> 6)) & 63;
        float* Gb = Gst + bucket * 32;
#pragma unroll
        for (int k = 0; k < 27; ++k) atomicAdd(&Gb[k], v[k]);
    }
}

// ---------------------------------------------------------------------------
// finalize1g: s1/t1 from 6x6 Gram + W1. 1 block x 64 threads.
// ---------------------------------------------------------------------------
__global__ void finalize1g_kernel(const float* __restrict__ Gst,
                                  const float* __restrict__ W1,
                                  const float* __restrict__ g,
                                  const float* __restrict__ bb,
                                  float* __restrict__ s, float* __restrict__ tt,
                                  float invM)
{
    __shared__ float G[27];
    int t = threadIdx.x;
    if (t < 27) {
        float v = 0.f;
        for (int bk = 0; bk < 64; ++bk) v += Gst[bk * 32 + t];
        G[t] = v;
    }
    __syncthreads();
    float w0 = W1[t * 6],     w1 = W1[t * 6 + 1], w2 = W1[t * 6 + 2];
    float w3 = W1[t * 6 + 3], w4 = W1[t * 6 + 4], w5 = W1[t * 6 + 5];
    float scol = w0 * G[0] + w1 * G[1] + w2 * G[2] +
                 w3 * G[3] + w4 * G[4] + w5 * G[5];
    float qcol =
        w0 * w0 * G[6]        + 2.f * w0 * w1 * G[7]  + 2.f * w0 * w2 * G[8]
      + 2.f * w0 * w3 * G[9]  + 2.f * w0 * w4 * G[10] + 2.f * w0 * w5 * G[11]
      + w1 * w1 * G[12]       + 2.f * w1 * w2 * G[13] + 2.f * w1 * w3 * G[14]
      + 2.f * w1 * w4 * G[15] + 2.f * w1 * w5 * G[16]
      + w2 * w2 * G[17]       + 2.f * w2 * w3 * G[18] + 2.f * w2 * w4 * G[19]
      + 2.f * w2 * w5 * G[20]
      + w3 * w3 * G[21]       + 2.f * w3 * w4 * G[22] + 2.f * w3 * w5 * G[23]
      + w4 * w4 * G[24]       + 2.f * w4 * w5 * G[25]
      + w5 * w5 * G[26];
    float mu  = scol * invM;
    float var = qcol * invM - mu * mu;
    float sc  = g[t] * rsqrtf(var + EPSBN);
    s[t]  = sc;
    tt[t] = bb[t] - mu * sc;
}

// ---------------------------------------------------------------------------
// cvt: fp32 -> f16 elementwise (weight pre-conversion).
// ---------------------------------------------------------------------------
__global__ __launch_bounds__(256) void cvt_kernel(const float* __restrict__ in,
                                                  _Float16* __restrict__ out)
{
    size_t gid = (size_t)blockIdx.x * 256 + threadIdx.x;
    float4 a = *(const float4*)(in + gid * 8);
    float4 b = *(const float4*)(in + gid * 8 + 4);
    half8 h;
    h[0] = (_Float16)a.x; h[1] = (_Float16)a.y;
    h[2] = (_Float16)a.z; h[3] = (_Float16)a.w;
    h[4] = (_Float16)b.x; h[5] = (_Float16)b.y;
    h[6] = (_Float16)b.z; h[7] = (_Float16)b.w;
    *(half8*)(out + gid * 8) = h;
}

// ---------------------------------------------------------------------------
// actmax3: fused act3 + maxk3 + inline finalize3 (st3 -> s3/t3 in prologue).
// ---------------------------------------------------------------------------
__global__ __launch_bounds__(256) void actmax3_kernel(const bf16_t* __restrict__ y3,
                                                      const float* __restrict__ stBuf,
                                                      const float* __restrict__ gg,
                                                      const float* __restrict__ bb,
                                                      float invM,
                                                      _Float16* __restrict__ y3a,
                                                      _Float16* __restrict__ c3)
{
    __shared__ __align__(16) float sl[128], tl[128];
    int t = threadIdx.x;
    if (t < 128) {
        float sum = 0.f, sq = 0.f;
        for (int bk = 0; bk < 64; ++bk) {
            sum += stBuf[bk * 256 + t];
            sq  += stBuf[bk * 256 + 128 + t];
        }
        float mu  = sum * invM;
        float var = sq * invM - mu * mu;
        float sc  = gg[t] * rsqrtf(var + EPSBN);
        sl[t] = sc;
        tl[t] = bb[t] - mu * sc;
    }
    __syncthreads();
    int bn = blockIdx.x * 16 + (t >> 4);
    int c0 = (t & 15) * 8;
    float4 sv0 = *(const float4*)(sl + c0);
    float4 sv1 = *(const float4*)(sl + c0 + 4);
    float4 tv0 = *(const float4*)(tl + c0);
    float4 tv1 = *(const float4*)(tl + c0 + 4);
    const bf16_t* src = y3 + (size_t)bn * KNN * 128 + c0;
    _Float16* dst = y3a + (size_t)bn * KNN * 128 + c0;
    float m0 = -1e30f, m1 = -1e30f, m2 = -1e30f, m3 = -1e30f;
    float m4 = -1e30f, m5 = -1e30f, m6 = -1e30f, m7 = -1e30f;
#pragma unroll 4
    for (int k = 0; k < KNN; ++k) {
        uint4 au = *(const uint4*)(src + (size_t)k * 128);
        float v0 = lrelu(fmaf(bf2f(au.x & 0xffff), sv0.x, tv0.x));
        float v1 = lrelu(fmaf(bf2f(au.x >> 16),    sv0.y, tv0.y));
        float v2 = lrelu(fmaf(bf2f(au.y & 0xffff), sv0.z, tv0.z));
        float v3 = lrelu(fmaf(bf2f(au.y >> 16),    sv0.w, tv0.w));
        float v4 = lrelu(fmaf(bf2f(au.z & 0xffff), sv1.x, tv1.x));
        float v5 = lrelu(fmaf(bf2f(au.z >> 16),    sv1.y, tv1.y));
        float v6 = lrelu(fmaf(bf2f(au.w & 0xffff), sv1.z, tv1.z));
        float v7 = lrelu(fmaf(bf2f(au.w >> 16),    sv1.w, tv1.w));
        half8 hv;
        hv[0] = (_Float16)v0; hv[1] = (_Float16)v1;
        hv[2] = (_Float16)v2; hv[3] = (_Float16)v3;
        hv[4] = (_Float16)v4; hv[5] = (_Float16)v5;
        hv[6] = (_Float16)v6; hv[7] = (_Float16)v7;
        *(half8*)(dst + (size_t)k * 128) = hv;
        m0 = fmaxf(m0, v0); m1 = fmaxf(m1, v1);
        m2 = fmaxf(m2, v2); m3 = fmaxf(m3, v3);
        m4 = fmaxf(m4, v4); m5 = fmaxf(m5, v5);
        m6 = fmaxf(m6, v6); m7 = fmaxf(m7, v7);
    }
    half8 hm;
    hm[0] = (_Float16)m0; hm[1] = (_Float16)m1;
    hm[2] = (_Float16)m2; hm[3] = (_Float16)m3;
    hm[4] = (_Float16)m4; hm[5] = (_Float16)m5;
    hm[6] = (_Float16)m6; hm[7] = (_Float16)m7;
    *(half8*)(c3 + (size_t)bn * 128 + c0) = hm;
}

// ---------------------------------------------------------------------------
// stats4: stage-4 stats via wide tile 128x256 (acc 2x16), copy staging.
// ---------------------------------------------------------------------------
__global__ __launch_bounds__(256, 2) void stats4_kernel(const _Float16* __restrict__ A,
                                                        const _Float16* __restrict__ Bh,
                                                        float* __restrict__ st)
{
    const int K = 128;
    __shared__ _Float16 Asm[128][LDA];     // 10 KB
    __shared__ _Float16 Bsm[256][LDA];     // 20 KB
    __shared__ float colsum[256], colsq[256];
    int t = threadIdx.x;
    int lane = t & 63, w = t >> 6;
    int quad = lane >> 4, l16 = lane & 15;
    size_t row0 = (size_t)blockIdx.x * 128;
    colsum[t] = 0.f; colsq[t] = 0.f;
    floatx4 acc[2][16];
#pragma unroll
    for (int mt = 0; mt < 2; ++mt)
#pragma unroll
        for (int nt = 0; nt < 16; ++nt)
            acc[mt][nt] = (floatx4){0.f, 0.f, 0.f, 0.f};

    for (int k0 = 0; k0 < K; k0 += 32) {
#pragma unroll
        for (int it = 0; it < 2; ++it) {           // A: 128x32 f16 copy
            int i = t + it * 256;
            int r = i >> 2, ko = (i & 3) * 8;
            *(uint4*)&Asm[r][ko] = *(const uint4*)(A + (row0 + r) * K + k0 + ko);
        }
#pragma unroll
        for (int it = 0; it < 4; ++it) {           // B: 256x32 f16 copy
            int i = t + it * 256;
            int n = i >> 2, seg = (i & 3) * 8;
            *(uint4*)&Bsm[n][seg] = *(const uint4*)(Bh + (size_t)n * K + k0 + seg);
        }
        __syncthreads();
        half8 af[2];
#pragma unroll
        for (int mt = 0; mt < 2; ++mt)
            af[mt] = *(const half8*)&Asm[w * 32 + mt * 16 + l16][quad * 8];
#pragma unroll
        for (int ng = 0; ng < 4; ++ng) {
            half8 bf[4];
#pragma unroll
            for (int j = 0; j < 4; ++j)
                bf[j] = *(const half8*)&Bsm[(ng * 4 + j) * 16 + l16][quad * 8];
#pragma unroll
            for (int mt = 0; mt < 2; ++mt)
#pragma unroll
                for (int j = 0; j < 4; ++j)
                    acc[mt][ng * 4 + j] = __builtin_amdgcn_mfma_f32_16x16x32_f16(
                        af[mt], bf[j], acc[mt][ng * 4 + j], 0, 0, 0);
        }
        __syncthreads();
    }
#pragma unroll
    for (int nt = 0; nt < 16; ++nt) {
        float s = 0.f, q = 0.f;
#pragma unroll
        for (int mt = 0; mt < 2; ++mt)
#pragma unroll
            for (int r = 0; r < 4; ++r) {
                float v = acc[mt][nt][r];
                s += v; q += v * v;
            }
        s += __shfl_xor(s, 16); q += __shfl_xor(q, 16);
        s += __shfl_xor(s, 32); q += __shfl_xor(q, 32);
        if (quad == 0) {
            atomicAdd(&colsum[nt * 16 + l16], s);
            atomicAdd(&colsq[nt * 16 + l16], q);
        }
    }
    __syncthreads();
    int bucket = blockIdx.x & 63;
    atomicAdd(&st[(size_t)bucket * 512 + t], colsum[t]);
    atomicAdd(&st[(size_t)bucket * 512 + 256 + t], colsq[t]);
}

// ---------------------------------------------------------------------------
// MFMA GEMM (s2/s3): act-staging from LDS s/t. If stBuf != null the s/t are
// computed in-prologue from the stats buckets (fused finalize); else copied
// from sIn/tIn. 128x64 tile, XCD swizzle.
// ---------------------------------------------------------------------------
__global__ __launch_bounds__(256) void gemm_mfma_bn(const bf16_t* __restrict__ A,
                                                    const float* __restrict__ W,
                                                    const float* __restrict__ sIn,
                                                    const float* __restrict__ tIn,
                                                    const float* __restrict__ stBuf,
                                                    const float* __restrict__ gg,
                                                    const float* __restrict__ bb,
                                                    float invM,
                                                    bf16_t* __restrict__ Y,
                                                    float* __restrict__ st,
                                                    int K, int Nout, int log2ncol)
{
    __shared__ _Float16 Asm[128][LDA];
    __shared__ _Float16 Bsm[64][LDA];
    __shared__ float colsum[64], colsq[64];
    __shared__ __align__(16) float sl[64], tl[64];
    int t = threadIdx.x;
    int lane = t & 63, w = t >> 6;
    int quad = lane >> 4, l16 = lane & 15;
    int p = blockIdx.x;
    int q = p >> 3;
    int c = q & ((1 << log2ncol) - 1);
    int rb = (p & 7) + 8 * (q >> log2ncol);    // row-block
    size_t row0 = (size_t)rb * 128;
    int col0 = c * 64;
    if (t < 64) {
        colsum[t] = 0.f; colsq[t] = 0.f;
        if (stBuf) {                           // fused finalize (Cin=64)
            float sum = 0.f, sq = 0.f;
            for (int bk = 0; bk < 64; ++bk) {
                sum += stBuf[bk * 128 + t];
                sq  += stBuf[bk * 128 + 64 + t];
            }
            float mu  = sum * invM;
            float var = sq * invM - mu * mu;
            float sc  = gg[t] * rsqrtf(var + EPSBN);
            sl[t] = sc;
            tl[t] = bb[t] - mu * sc;
        } else {
            sl[t] = sIn[t];
            tl[t] = tIn[t];
        }
    }
    __syncthreads();
    floatx4 acc[2][4];
#pragma unroll
    for (int mt = 0; mt < 2; ++mt)
#pragma unroll
        for (int nt = 0; nt < 4; ++nt)
            acc[mt][nt] = (floatx4){0.f, 0.f, 0.f, 0.f};

    for (int k0 = 0; k0 < K; k0 += 32) {
#pragma unroll
        for (int it = 0; it < 2; ++it) {           // A: 128x32 -> act -> f16
            int i = t + it * 256;
            int r = i >> 2, ko = (i & 3) * 8;
            uint4 au = *(const uint4*)(A + (row0 + r) * K + k0 + ko);
            float4 sv0 = *(const float4*)(sl + k0 + ko);
            float4 sv1 = *(const float4*)(sl + k0 + ko + 4);
            float4 tv0 = *(const float4*)(tl + k0 + ko);
            float4 tv1 = *(const float4*)(tl + k0 + ko + 4);
            half8 hv;
            hv[0] = (_Float16)lrelu(fmaf(bf2f(au.x & 0xffff), sv0.x, tv0.x));
            hv[1] = (_Float16)lrelu(fmaf(bf2f(au.x >> 16),    sv0.y, tv0.y));
            hv[2] = (_Float16)lrelu(fmaf(bf2f(au.y & 0xffff), sv0.z, tv0.z));
            hv[3] = (_Float16)lrelu(fmaf(bf2f(au.y >> 16),    sv0.w, tv0.w));
            hv[4] = (_Float16)lrelu(fmaf(bf2f(au.z & 0xffff), sv1.x, tv1.x));
            hv[5] = (_Float16)lrelu(fmaf(bf2f(au.z >> 16),    sv1.y, tv1.y));
            hv[6] = (_Float16)lrelu(fmaf(bf2f(au.w & 0xffff), sv1.z, tv1.z));
            hv[7] = (_Float16)lrelu(fmaf(bf2f(au.w >> 16),    sv1.w, tv1.w));
            *(half8*)&Asm[r][ko] = hv;
        }
#pragma unroll
        for (int it = 0; it < 2; ++it) {           // B: 64x32 fp32 -> f16
            int i = t + it * 256;
            int n = i >> 3, seg = (i & 7) * 4;
            float4 bv = *(const float4*)(W + (size_t)(col0 + n) * K + k0 + seg);
            half4v h;
            h[0] = (_Float16)bv.x; h[1] = (_Float16)bv.y;
            h[2] = (_Float16)bv.z; h[3] = (_Float16)bv.w;
            *(half4v*)&Bsm[n][seg] = h;
        }
        __syncthreads();
        half8 af[2], bf[4];
#pragma unroll
        for (int mt = 0; mt < 2; ++mt)
            af[mt] = *(const half8*)&Asm[w * 32 + mt * 16 + l16][quad * 8];
#pragma unroll
        for (int nt = 0; nt < 4; ++nt)
            bf[nt] = *(const half8*)&Bsm[nt * 16 + l16][quad * 8];
#pragma unroll
        for (int mt = 0; mt < 2; ++mt)
#pragma unroll
            for (int nt = 0; nt < 4; ++nt)
                acc[mt][nt] = __builtin_amdgcn_mfma_f32_16x16x32_f16(
                    af[mt], bf[nt], acc[mt][nt], 0, 0, 0);
        __syncthreads();
    }
#pragma unroll
    for (int mt = 0; mt < 2; ++mt)
#pragma unroll
        for (int nt = 0; nt < 4; ++nt)
#pragma unroll
            for (int r = 0; r < 4; ++r) {
                size_t row = row0 + w * 32 + mt * 16 + quad * 4 + r;
                Y[row * Nout + col0 + nt * 16 + l16] = f2bf(acc[mt][nt][r]);
            }
#pragma unroll
    for (int nt = 0; nt < 4; ++nt) {
        float s = 0.f, q2 = 0.f;
#pragma unroll
        for (int mt = 0; mt < 2; ++mt)
#pragma unroll
            for (int r = 0; r < 4; ++r) {
                float v = acc[mt][nt][r];
                s += v; q2 += v * v;
            }
        s += __shfl_xor(s, 16); q2 += __shfl_xor(q2, 16);
        s += __shfl_xor(s, 32); q2 += __shfl_xor(q2, 32);
        if (quad == 0) {
            atomicAdd(&colsum[nt * 16 + l16], s);
            atomicAdd(&colsq[nt * 16 + l16], q2);
        }
    }
    __syncthreads();
    int bucket = rb & 63;
    if (t < 64) {
        atomicAdd(&st[(size_t)bucket * 2 * Nout + col0 + t], colsum[t]);
        atomicAdd(&st[(size_t)bucket * 2 * Nout + Nout + col0 + t], colsq[t]);
    }
}

// ---------------------------------------------------------------------------
// Stage-4 fused pass 2 (MFMA) + inline finalize4 (st4 -> s4/t4 for its cols).
// ---------------------------------------------------------------------------
__global__ __launch_bounds__(256) void gemm4_mfma(const _Float16* __restrict__ A,
                                                  const float* __restrict__ W,
                                                  const float* __restrict__ stBuf,
                                                  const float* __restrict__ gg,
                                                  const float* __restrict__ bb,
                                                  float invM,
                                                  _Float16* __restrict__ slab4)
{
    const int K = 128;
    __shared__ __align__(16) unsigned char smem[320 * 68 * 2];   // 43520 B
    _Float16 (*Asm)[LDA] = (_Float16 (*)[LDA])smem;              // 25600 B
    _Float16 (*Bsm)[LDA] = (_Float16 (*)[LDA])(smem + 320 * LDA * 2); // +5120
    _Float16 (*tile)[68] = (_Float16 (*)[68])smem;               // post-loop
    __shared__ float sl[64], tl[64];
    int t = threadIdx.x;
    int lane = t & 63, w = t >> 6;
    int quad = lane >> 4, l16 = lane & 15;
    int p = blockIdx.x;
    int q = p >> 3;
    int c = q & 3;
    int rb = (p & 7) + 8 * (q >> 2);           // row-block 0..1023
    size_t row0 = (size_t)rb * 320;
    int col0 = c * 64;
    if (t < 64) {                              // fused finalize4 (C=256)
        int cc = col0 + t;
        float sum = 0.f, sq = 0.f;
        for (int bk = 0; bk < 64; ++bk) {
            sum += stBuf[bk * 512 + cc];
            sq  += stBuf[bk * 512 + 256 + cc];
        }
        float mu  = sum * invM;
        float var = sq * invM - mu * mu;
        float sc  = gg[cc] * rsqrtf(var + EPSBN);
        sl[t] = sc;
        tl[t] = bb[cc] - mu * sc;
    }
    floatx4 acc[5][4];
#pragma unroll
    for (int mt = 0; mt < 5; ++mt)
#pragma unroll
        for (int nt = 0; nt < 4; ++nt)
            acc[mt][nt] = (floatx4){0.f, 0.f, 0.f, 0.f};

    for (int k0 = 0; k0 < K; k0 += 32) {
#pragma unroll
        for (int it = 0; it < 5; ++it) {           // A: 320x32 plain f16 copy
            int i = t + it * 256;
            int r = i >> 2, ko = (i & 3) * 8;
            uint4 au = *(const uint4*)(A + (row0 + r) * K + k0 + ko);
            *(uint4*)&Asm[r][ko] = au;
        }
#pragma unroll
        for (int it = 0; it < 2; ++it) {           // B: 64x32
            int i = t + it * 256;
            int n = i >> 3, seg = (i & 7) * 4;
            float4 bv = *(const float4*)(W + (size_t)(col0 + n) * K + k0 + seg);
            half4v h;
            h[0] = (_Float16)bv.x; h[1] = (_Float16)bv.y;
            h[2] = (_Float16)bv.z; h[3] = (_Float16)bv.w;
            *(half4v*)&Bsm[n][seg] = h;
        }
        __syncthreads();
        half8 af[5], bf[4];
#pragma unroll
        for (int mt = 0; mt < 5; ++mt)
            af[mt] = *(const half8*)&Asm[w * 80 + mt * 16 + l16][quad * 8];
#pragma unroll
        for (int nt = 0; nt < 4; ++nt)
            bf[nt] = *(const half8*)&Bsm[nt * 16 + l16][quad * 8];
#pragma unroll
        for (int mt = 0; mt < 5; ++mt)
#pragma unroll
            for (int nt = 0; nt < 4; ++nt)
                acc[mt][nt] = __builtin_amdgcn_mfma_f32_16x16x32_f16(
                    af[mt], bf[nt], acc[mt][nt], 0, 0, 0);
        __syncthreads();                           // also guards smem reuse
    }
    float s4c[4], t4c[4];
#pragma unroll
    for (int nt = 0; nt < 4; ++nt) {
        s4c[nt] = sl[nt * 16 + l16];
        t4c[nt] = tl[nt * 16 + l16];
    }
#pragma unroll
    for (int mt = 0; mt < 5; ++mt)
#pragma unroll
        for (int nt = 0; nt < 4; ++nt)
#pragma unroll
            for (int r = 0; r < 4; ++r) {
                int rl = w * 80 + mt * 16 + quad * 4 + r;
                tile[rl][nt * 16 + l16] =
                    (_Float16)lrelu(fmaf(acc[mt][nt][r], s4c[nt], t4c[nt]));
            }
    __syncthreads();
    int col = t & 63;
#pragma unroll
    for (int g = 0; g < 4; ++g) {
        int pt = (t >> 6) * 4 + g;                 // 0..15
        float m = -1e30f;
#pragma unroll
        for (int k = 0; k < KNN; ++k)
            m = fmaxf(m, (float)tile[pt * KNN + k][col]);
        slab4[((size_t)rb * 16 + pt) * 256 + col0 + col] = (_Float16)m;
    }
}

// ---------------------------------------------------------------------------
// Final GEMM wide: unchanged from round 10.
// ---------------------------------------------------------------------------
__global__ __launch_bounds__(256, 2) void gemm5_wide(const _Float16* __restrict__ c1,
                                                     const _Float16* __restrict__ c2,
                                                     const _Float16* __restrict__ c3,
                                                     const _Float16* __restrict__ c4,
                                                     const _Float16* __restrict__ W5h,
                                                     float* __restrict__ Y,
                                                     float* __restrict__ st)
{
    const int K = 512, Nout = 1024;
    __shared__ _Float16 Asm[128][LDA];     // 10 KB
    __shared__ _Float16 Bsm[256][LDA];     // 20 KB
    __shared__ float colsum[256], colsq[256];
    int t = threadIdx.x;
    int lane = t & 63, w = t >> 6;
    int quad = lane >> 4, l16 = lane & 15;
    size_t row0 = (size_t)blockIdx.y * 128;
    int col0 = blockIdx.x * 256;
    colsum[t] = 0.f; colsq[t] = 0.f;
    floatx4 acc[2][16];
#pragma unroll
    for (int mt = 0; mt < 2; ++mt)
#pragma unroll
        for (int nt = 0; nt < 16; ++nt)
            acc[mt][nt] = (floatx4){0.f, 0.f, 0.f, 0.f};

    for (int k0 = 0; k0 < K; k0 += 32) {
        const _Float16* base; int stride, off;
        if (k0 < 64)       { base = c1; stride = 64;  off = 0; }
        else if (k0 < 128) { base = c2; stride = 64;  off = 64; }
        else if (k0 < 256) { base = c3; stride = 128; off = 128; }
        else               { base = c4; stride = 256; off = 256; }
#pragma unroll
        for (int it = 0; it < 2; ++it) {           // A: 128x32 f16 copy
            int i = t + it * 256;
            int r = i >> 2, ko = (i & 3) * 8;
            *(uint4*)&Asm[r][ko] = *(const uint4*)(base
                + (size_t)(row0 + r) * stride + (k0 - off) + ko);
        }
#pragma unroll
        for (int it = 0; it < 4; ++it) {           // B: 256x32 f16 copy
            int i = t + it * 256;
            int n = i >> 2, seg = (i & 3) * 8;
            *(uint4*)&Bsm[n][seg] = *(const uint4*)(W5h
                + (size_t)(col0 + n) * K + k0 + seg);
        }
        __syncthreads();
        half8 af[2];
#pragma unroll
        for (int mt = 0; mt < 2; ++mt)
            af[mt] = *(const half8*)&Asm[w * 32 + mt * 16 + l16][quad * 8];
#pragma unroll
        for (int ng = 0; ng < 4; ++ng) {
            half8 bf[4];
#pragma unroll
            for (int j = 0; j < 4; ++j)
                bf[j] = *(const half8*)&Bsm[(ng * 4 + j) * 16 + l16][quad * 8];
#pragma unroll
            for (int mt = 0; mt < 2; ++mt)
#pragma unroll
                for (int j = 0; j < 4; ++j)
                    acc[mt][ng * 4 + j] = __builtin_amdgcn_mfma_f32_16x16x32_f16(
                        af[mt], bf[j], acc[mt][ng * 4 + j], 0, 0, 0);
        }
        __syncthreads();
    }
#pragma unroll
    for (int mt = 0; mt < 2; ++mt)
#pragma unroll
        for (int nt = 0; nt < 16; ++nt)
#pragma unroll
            for (int r = 0; r < 4; ++r) {
                size_t row = row0 + w * 32 + mt * 16 + quad * 4 + r;
                Y[row * Nout + col0 + nt * 16 + l16] = acc[mt][nt][r];
            }
#pragma unroll
    for (int nt = 0; nt < 16; ++nt) {
        float s = 0.f, q = 0.f;
#pragma unroll
        for (int mt = 0; mt < 2; ++mt)
#pragma unroll
            for (int r = 0; r < 4; ++r) {
                float v = acc[mt][nt][r];
                s += v; q += v * v;
            }
        s += __shfl_xor(s, 16); q += __shfl_xor(q, 16);
        s += __shfl_xor(s, 32); q += __shfl_xor(q, 32);
        if (quad == 0) {
            atomicAdd(&colsum[nt * 16 + l16], s);
            atomicAdd(&colsq[nt * 16 + l16], q);
        }
    }
    __syncthreads();
    int bucket = blockIdx.y & 63;
    atomicAdd(&st[(size_t)bucket * 2 * Nout + col0 + t], colsum[t]);
    atomicAdd(&st[(size_t)bucket * 2 * Nout + Nout + col0 + t], colsq[t]);
}

// ---------------------------------------------------------------------------
// maxk (stages 1/2): if stBuf != null, s/t computed in-prologue (fused
// finalize, C=64); else from sIn/tIn.
// ---------------------------------------------------------------------------
__global__ __launch_bounds__(256) void maxk_kernel(const bf16_t* __restrict__ Y,
                                                   const float* __restrict__ sIn,
                                                   const float* __restrict__ tIn,
                                                   const float* __restrict__ stBuf,
                                                   const float* __restrict__ gg,
                                                   const float* __restrict__ bb,
                                                   float invM,
                                                   _Float16* __restrict__ slab,
                                                   int C, int logC)
{
    __shared__ float sl[64], tl[64];
    int t = threadIdx.x;
    if (t < 64) {
        if (stBuf) {
            float sum = 0.f, sq = 0.f;
            for (int bk = 0; bk < 64; ++bk) {
                sum += stBuf[bk * 128 + t];
                sq  += stBuf[bk * 128 + 64 + t];
            }
            float mu  = sum * invM;
            float var = sq * invM - mu * mu;
            float sc  = gg[t] * rsqrtf(var + EPSBN);
            sl[t] = sc;
            tl[t] = bb[t] - mu * sc;
        } else {
            sl[t] = sIn[t];
            tl[t] = tIn[t];
        }
    }
    __syncthreads();
    int gid = blockIdx.x * 256 + t;
    int c = gid & (C - 1);
    int bn = gid >> logC;
    float sc = sl[c], tc = tl[c];
    const bf16_t* p = Y + (size_t)bn * KNN * C + c;
    float m = -1e30f;
#pragma unroll
    for (int kk = 0; kk < KNN; ++kk) {
        float v = fmaf(bf2f(p[(size_t)kk * C]), sc, tc);
        m = fmaxf(m, lrelu(v));
    }
    slab[(size_t)bn * C + c] = (_Float16)m;
}

// ---------------------------------------------------------------------------
// out + inline finalize5 (st5 -> s5/t5 for its 32 cols).
// ---------------------------------------------------------------------------
__global__ __launch_bounds__(256) void out_kernel(const float* __restrict__ y5,
                                                  const float* __restrict__ stBuf,
                                                  const float* __restrict__ gg,
                                                  const float* __restrict__ bb,
                                                  float invM,
                                                  float* __restrict__ out)
{
    __shared__ float tile[32][65];
    __shared__ float sl[32], tl[32];
    int t = threadIdx.x;
    int b = blockIdx.z;
    int o0 = blockIdx.y * 32;
    int n0 = blockIdx.x * 64;
    if (t < 32) {                              // fused finalize5 (C=1024)
        int cc = o0 + t;
        float sum = 0.f, sq = 0.f;
        for (int bk = 0; bk < 64; ++bk) {
            sum += stBuf[(size_t)bk * 2048 + cc];
            sq  += stBuf[(size_t)bk * 2048 + 1024 + cc];
        }
        float mu  = sum * invM;
        float var = sq * invM - mu * mu;
        float sc  = gg[cc] * rsqrtf(var + EPSBN);
        sl[t] = sc;
        tl[t] = bb[cc] - mu * sc;
    }
#pragma unroll
    for (int p = 0; p < 8; ++p) {
        int ol = t & 31, nl = (t >> 5) + 8 * p;
        tile[ol][nl] = y5[((size_t)b * NPTS + n0 + nl) * 1024 + o0 + ol];
    }
    __syncthreads();
#pragma unroll
    for (int p = 0; p < 8; ++p) {
        int nl = t & 63, ol = (t >> 6) + 4 * p;
        float v = fmaf(tile[ol][nl], sl[ol], tl[ol]);
        out[(size_t)b * 1024 * NPTS + (size_t)(o0 + ol) * NPTS + n0 + nl] = lrelu(v);
    }
}

// ---------------------------------------------------------------------------
extern "C" void kernel_launch(void* const* d_in, const int* in_sizes, int n_in,
                              void* d_out, int out_size, void* d_ws, size_t ws_size,
                              hipStream_t stream)
{
    const float* x  = (const float*)d_in[0];
    const float* W1 = (const float*)d_in[1];
    const float* g1 = (const float*)d_in[2];  const float* b1 = (const float*)d_in[3];
    const float* W2 = (const float*)d_in[4];
    const float* g2 = (const float*)d_in[5];  const float* b2 = (const float*)d_in[6];
    const float* W3 = (const float*)d_in[7];
    const float* g3 = (const float*)d_in[8];  const float* b3 = (const float*)d_in[9];
    const float* W4 = (const float*)d_in[10];
    const float* g4 = (const float*)d_in[11]; const float* b4 = (const float*)d_in[12];
    const float* W5 = (const float*)d_in[13];
    const float* g5 = (const float*)d_in[14]; const float* b5 = (const float*)d_in[15];
    float* out = (float*)d_out;

    // -------- workspace layout (~195 MB total) --------
    char* p = (char*)d_ws;
    int* idx = (int*)p;                 p += (size_t)M1 * 4;                 // 1.3 MB
    bf16_t* y1 = (bf16_t*)p;
    float*  y5 = (float*)p;
    _Float16* y3a = (_Float16*)p;       p += (size_t)M1 * 64 * 2;           // arena A
    bf16_t* y2 = (bf16_t*)p;            p += (size_t)M1 * 64 * 2;
    bf16_t* y3 = (bf16_t*)p;            p += (size_t)M1 * 128 * 2;
    _Float16* c1 = (_Float16*)p;        p += (size_t)M5 * 64 * 4;           // f16 slabs
    _Float16* c2 = (_Float16*)p;        p += (size_t)M5 * 64 * 4;
    _Float16* c3 = (_Float16*)p;        p += (size_t)M5 * 128 * 4;
    _Float16* c4 = (_Float16*)p;        p += (size_t)M5 * 256 * 4;
    float* st1 = (float*)p;             p += 64 * 2 * 64 * 4;               // (unused)
    float* st2 = (float*)p;             p += 64 * 2 * 64 * 4;
    float* st3 = (float*)p;             p += 64 * 2 * 128 * 4;
    float* st4 = (float*)p;             p += 64 * 2 * 256 * 4;
    float* st5 = (float*)p;             p += 64 * 2 * 1024 * 4;
    float* Gst = (float*)p;             p += 64 * 32 * 4;                   // 8 KB
    _Float16* W4h = (_Float16*)p;       p += 256 * 128 * 2;                 // 64 KB
    _Float16* W5h = (_Float16*)p;       p += (size_t)1024 * 512 * 2;        // 1 MB
    float* s1 = (float*)p; p += 64 * 4;   float* t1 = (float*)p; p += 64 * 4;
    // y3a (M1*128 fp16 = 84 MB) aliases arena A (y1) + y2: y1/y2 are dead
    // before stage 4; y5 overwrites the arena only after gemm4 completes.

    size_t statsBytes = (size_t)(64 * 2 * (64 + 64 + 128 + 256 + 1024)) * 4
                      + 64 * 32 * 4;
    hipMemsetAsync(st1, 0, statsBytes, stream);

    const float invM14 = 1.0f / (float)M1;
    const float invM5  = 1.0f / (float)M5;

    // weight pre-conversion (f32 -> f16)
    cvt_kernel<<<(256 * 128) / 2048, 256, 0, stream>>>(W4, W4h);
    cvt_kernel<<<(1024 * 512) / 2048, 256, 0, stream>>>(W5, W5h);

    knn_kernel<<<M5 / 16, 512, 0, stream>>>(x, idx);

    // stage 1: row-per-thread conv + Gram stats
    conv1_kernel<<<M1 / 256, 256, 0, stream>>>(x, idx, W1, y1, Gst);
    finalize1g_kernel<<<1, 64, 0, stream>>>(Gst, W1, g1, b1, s1, t1, invM14);
    maxk_kernel<<<(M5 * 64) / 256, 256, 0, stream>>>(y1, s1, t1,
                                                     nullptr, nullptr, nullptr,
                                                     0.f, c1, 64, 6);

    // stage 2 (ncol=1 -> swizzle identity; s1/t1 direct)
    gemm_mfma_bn<<<M1 / 128, 256, 0, stream>>>(y1, W2, s1, t1,
                                               nullptr, nullptr, nullptr, 0.f,
                                               y2, st2, 64, 64, 0);
    maxk_kernel<<<(M5 * 64) / 256, 256, 0, stream>>>(y2, nullptr, nullptr,
                                                     st2, g2, b2, invM14,
                                                     c2, 64, 6);

    // stage 3 (ncol=2, XCD-swizzled; fused finalize2 in prologue)
    gemm_mfma_bn<<<(M1 / 128) * 2, 256, 0, stream>>>(y2, W3, nullptr, nullptr,
                                                     st2, g2, b2, invM14,
                                                     y3, st3, 64, 128, 1);

    // stage 4: fused act+maxk (finalize3 inline) -> wide stats -> gemm4
    actmax3_kernel<<<M5 / 16, 256, 0, stream>>>(y3, st3, g3, b3, invM14, y3a, c3);
    stats4_kernel<<<M1 / 128, 256, 0, stream>>>(y3a, W4h, st4);
    gemm4_mfma<<<(M1 / 320) * 4, 256, 0, stream>>>(y3a, W4, st4, g4, b4,
                                                   invM14, c4);

    // stage 5 (wide tile; finalize5 fused into out)
    gemm5_wide<<<dim3(4, M5 / 128), 256, 0, stream>>>(c1, c2, c3, c4, W5h, y5, st5);
    out_kernel<<<dim3(NPTS / 64, 1024 / 32, BATCH), 256, 0, stream>>>(y5, st5,
                                                                      g5, b5,
                                                                      invM5, out);
}

// Round 13
// 492.850 us; speedup vs baseline: 1.0840x; 1.0840x over previous
//
#include <hip/hip_runtime.h>

#define BATCH 8
#define NPTS  2048
#define KNN   20
#define M1    (BATCH * NPTS * KNN)   // 327680 rows for conv stages
#define M5    (BATCH * NPTS)         // 16384 rows for final projection
#define EPSBN 1e-5f
#define LDA   40                      // padded LDS k-stride (halfs): 2-way max aliasing

typedef unsigned short bf16_t;
typedef _Float16 half8 __attribute__((ext_vector_type(8)));
typedef _Float16 half4v __attribute__((ext_vector_type(4)));
typedef float    floatx4 __attribute__((ext_vector_type(4)));

__device__ __forceinline__ float bf2f(bf16_t u) {
    return __uint_as_float(((unsigned int)u) << 16);
}
__device__ __forceinline__ bf16_t f2bf(float f) {
    unsigned int u = __float_as_uint(f);
    return (bf16_t)((u + 0x7fffu + ((u >> 16) & 1u)) >> 16);
}
__device__ __forceinline__ float lrelu(float v) { return v >= 0.f ? v : 0.2f * v; }

// ---------------------------------------------------------------------------
// KNN v7 (unchanged).
// ---------------------------------------------------------------------------
#define DPPMAX(v, ctrl)                                                      \
    {                                                                        \
        unsigned int o_ = (unsigned int)__builtin_amdgcn_update_dpp(         \
            (int)(v), (int)(v), ctrl, 0xF, 0xF, false);                      \
        if (o_ > (v)) (v) = o_;                                              \
    }
#define SWZMAX32(v)                                                          \
    {                                                                        \
        unsigned int o_ = (unsigned int)__builtin_amdgcn_ds_swizzle(         \
            (int)(v), 0x401F);                                               \
        if (o_ > (v)) (v) = o_;                                              \
    }
#define GRPMAX32(v)                                                          \
    DPPMAX(v, 0xB1)  /* quad_perm(1,0,3,2): xor1  */                         \
    DPPMAX(v, 0x4E)  /* quad_perm(2,3,0,1): xor2  */                         \
    DPPMAX(v, 0x141) /* row_half_mirror:    xor7  */                         \
    DPPMAX(v, 0x140) /* row_mirror:         xor15 */                         \
    SWZMAX32(v)      /* ds_swizzle:         xor16 */

#define DIST_KEY(pm, idxv, kp)                                               \
    {                                                                        \
        float inner_ = __fadd_rn(__fadd_rn(__fmul_rn(xn0, (pm).x),           \
                                           __fmul_rn(xn1, (pm).y)),          \
                                 __fmul_rn(xn2, (pm).z));                    \
        float d_ = __fsub_rn(__fsub_rn(__fmul_rn(2.0f, inner_), xxn),        \
                             (pm).w);                                        \
        unsigned int s_ = ~__float_as_uint(d_);                              \
        kp = ((unsigned long long)s_ << 32) | (unsigned int)(idxv);          \
    }

#define INS3(kp)                                                             \
    {                                                                        \
        bool c1_ = (kp) > k1, c2_ = (kp) > k2, c3_ = (kp) > k3;              \
        k3 = c2_ ? k2 : (c3_ ? (kp) : k3);                                   \
        k2 = c1_ ? k1 : (c2_ ? (kp) : k2);                                   \
        k1 = c1_ ? (kp) : k1;                                                \
    }

__global__ __launch_bounds__(512, 8) void knn_kernel(const float* __restrict__ x,
                                                     int* __restrict__ idx)
{
    __shared__ float4 pts[NPTS];              // 32 KB
    int t = threadIdx.x;
    int b = blockIdx.x >> 7;                  // 128 blocks per batch
    int base = (blockIdx.x & 127) * 16;       // 16 points per block (2/wave)
    const float* xb = x + (size_t)b * 3 * NPTS;
    for (int i = t; i < NPTS; i += 512) {
        float a0 = xb[i], a1 = xb[NPTS + i], a2 = xb[2 * NPTS + i];
        float xx = __fadd_rn(__fadd_rn(__fmul_rn(a0, a0), __fmul_rn(a1, a1)),
                             __fmul_rn(a2, a2));
        pts[i] = make_float4(a0, a1, a2, xx);
    }
    __syncthreads();
    int w = t >> 6, lane = t & 63;
    int gl = lane & 31;                       // lane within 32-lane group
    int n = base + w * 2 + (lane >> 5);       // this group's point
    float4 pn = pts[n];
    float xn0 = pn.x, xn1 = pn.y, xn2 = pn.z, xxn = pn.w;
    unsigned long long k1 = 0ULL, k2 = 0ULL, k3 = 0ULL;  // 0 < any real key
    unsigned long long emask = 0ULL;          // extracted slots (j index, 64 bits)

    // ---- distance phase: 8 candidates per iteration (batched LDS loads) ----
    {
        const float4* pp = pts + gl;
        unsigned int idxv = 2047u - (unsigned int)gl;   // NPTS-1-m for m=gl
        for (int jo = 0; jo < 64; jo += 8) {
            float4 p0 = pp[0],   p1 = pp[32],  p2 = pp[64],  p3 = pp[96];
            float4 p4 = pp[128], p5 = pp[160], p6 = pp[192], p7 = pp[224];
            pp += 256;
            unsigned long long kp0, kp1, kp2, kp3, kp4, kp5, kp6, kp7;
            DIST_KEY(p0, idxv,        kp0);
            DIST_KEY(p1, idxv - 32u,  kp1);
            DIST_KEY(p2, idxv - 64u,  kp2);
            DIST_KEY(p3, idxv - 96u,  kp3);
            DIST_KEY(p4, idxv - 128u, kp4);
            DIST_KEY(p5, idxv - 160u, kp5);
            DIST_KEY(p6, idxv - 192u, kp6);
            DIST_KEY(p7, idxv - 224u, kp7);
            INS3(kp0);
            INS3(kp1);
            INS3(kp2);
            INS3(kp3);
            INS3(kp4);
            INS3(kp5);
            INS3(kp6);
            INS3(kp7);
            idxv -= 256u;
        }
    }

    int* op = idx + (size_t)(b * NPTS + n) * KNN;

    // ---- round 0: self-point (s=0xFFFFFFFF is the strict max key) ----
    if (gl == 0) op[0] = n;
    if ((n & 31) == gl) {                     // self always is owner's k1
        emask |= 1ULL << (n >> 5);
        k1 = k2; k2 = k3; k3 = 0ULL;          // 64 cands/lane -> k2,k3 valid
    }

    for (int r = 1; r < KNN; ++r) {
        unsigned int s1 = (unsigned int)(k1 >> 32);
        unsigned int sm = s1;
        GRPMAX32(sm)                          // global max distance-key
        unsigned int lm = (sm == s1) ? (unsigned int)k1 : 0u;
        GRPMAX32(lm)                          // max idxv among s==sm lanes
        int m_ex = 2047 - (int)(lm & 0x7FFu);
        if (gl == 0) op[r] = m_ex;
        if (r < KNN - 1 && (m_ex & 31) == gl) {   // owner lane updates top-3
            emask |= 1ULL << (m_ex >> 5);
            if (k2 != 0ULL) { k1 = k2; k2 = k3; k3 = 0ULL; }
            else {                             // rare: recompute survivors
                k1 = 0ULL; k2 = 0ULL; k3 = 0ULL;
                const float4* pr = pts + gl;
                unsigned int idr = 2047u - (unsigned int)gl;
                for (int j = 0; j < 64; ++j) {
                    if (!(emask & (1ULL << j))) {
                        float4 pm = pr[j * 32];
                        unsigned long long kr;
                        DIST_KEY(pm, idr - (unsigned int)(j * 32), kr);
                        INS3(kr);
                    }
                }
            }
        }
    }
}

// ---------------------------------------------------------------------------
// conv1 (round-10 proven version): edge features * W1 -> y1 bf16 + stats
// ---------------------------------------------------------------------------
__global__ __launch_bounds__(256) void conv1_kernel(const float* __restrict__ x,
                                                    const int* __restrict__ idx,
                                                    const float* __restrict__ W1,
                                                    bf16_t* __restrict__ Y,
                                                    float* __restrict__ st)
{
    __shared__ float f[64][6];
    __shared__ float w[384];
    __shared__ float red[256];
    int t = threadIdx.x;
    for (int i = t; i < 384; i += 256) w[i] = W1[i];
    int row0 = blockIdx.x * 64;
    if (t < 64) {
        int gr = row0 + t;
        int bn = gr / KNN;
        int j = idx[gr];
        int b = bn >> 11, n = bn & (NPTS - 1);
        const float* xb = x + (size_t)b * 3 * NPTS;
        float xi0 = xb[n], xi1 = xb[NPTS + n], xi2 = xb[2 * NPTS + n];
        float xj0 = xb[j], xj1 = xb[NPTS + j], xj2 = xb[2 * NPTS + j];
        f[t][0] = xj0 - xi0; f[t][1] = xj1 - xi1; f[t][2] = xj2 - xi2;
        f[t][3] = xi0;       f[t][4] = xi1;       f[t][5] = xi2;
    }
    __syncthreads();
    int tx = t & 63, ty = t >> 6;
    float wc0 = w[tx * 6 + 0], wc1 = w[tx * 6 + 1], wc2 = w[tx * 6 + 2];
    float wc3 = w[tx * 6 + 3], wc4 = w[tx * 6 + 4], wc5 = w[tx * 6 + 5];
    float ssum = 0.f, ssq = 0.f;
#pragma unroll
    for (int i = 0; i < 16; ++i) {
        int r = ty * 16 + i;
        float yv = f[r][0] * wc0 + f[r][1] * wc1 + f[r][2] * wc2 +
                   f[r][3] * wc3 + f[r][4] * wc4 + f[r][5] * wc5;
        Y[(size_t)(row0 + r) * 64 + tx] = f2bf(yv);
        ssum += yv; ssq += yv * yv;
    }
    int bucket = blockIdx.x & 63;
    red[ty * 64 + tx] = ssum;
    __syncthreads();
    if (t < 64) {
        float v = red[t] + red[64 + t] + red[128 + t] + red[192 + t];
        atomicAdd(&st[bucket * 128 + t], v);
    }
    __syncthreads();
    red[ty * 64 + tx] = ssq;
    __syncthreads();
    if (t < 64) {
        float v = red[t] + red[64 + t] + red[128 + t] + red[192 + t];
        atomicAdd(&st[bucket * 128 + 64 + t], v);
    }
}

// ---------------------------------------------------------------------------
// cvt: fp32 -> f16 elementwise (weight pre-conversion; same rounding op as
// the old in-staging cvt -> bit-identical downstream).
// ---------------------------------------------------------------------------
__global__ __launch_bounds__(256) void cvt_kernel(const float* __restrict__ in,
                                                  _Float16* __restrict__ out)
{
    size_t gid = (size_t)blockIdx.x * 256 + threadIdx.x;
    float4 a = *(const float4*)(in + gid * 8);
    float4 b = *(const float4*)(in + gid * 8 + 4);
    half8 h;
    h[0] = (_Float16)a.x; h[1] = (_Float16)a.y;
    h[2] = (_Float16)a.z; h[3] = (_Float16)a.w;
    h[4] = (_Float16)b.x; h[5] = (_Float16)b.y;
    h[6] = (_Float16)b.z; h[7] = (_Float16)b.w;
    *(half8*)(out + gid * 8) = h;
}

// ---------------------------------------------------------------------------
// actmax3: fused act3 + maxk3. Per element v = lrelu(fmaf(bf2f(y3), s3, t3));
// writes y3a = f16(v) and c3[bn][c] = f16(max_k v). One y3 read (was two).
// Block = 16 points x 16 col-groups of 8. Bit-identical FP to the split pair.
// ---------------------------------------------------------------------------
__global__ __launch_bounds__(256) void actmax3_kernel(const bf16_t* __restrict__ y3,
                                                      const float* __restrict__ s3,
                                                      const float* __restrict__ t3,
                                                      _Float16* __restrict__ y3a,
                                                      _Float16* __restrict__ c3)
{
    int t = threadIdx.x;
    int bn = blockIdx.x * 16 + (t >> 4);
    int c0 = (t & 15) * 8;
    float4 sv0 = *(const float4*)(s3 + c0);
    float4 sv1 = *(const float4*)(s3 + c0 + 4);
    float4 tv0 = *(const float4*)(t3 + c0);
    float4 tv1 = *(const float4*)(t3 + c0 + 4);
    const bf16_t* src = y3 + (size_t)bn * KNN * 128 + c0;
    _Float16* dst = y3a + (size_t)bn * KNN * 128 + c0;
    float m0 = -1e30f, m1 = -1e30f, m2 = -1e30f, m3 = -1e30f;
    float m4 = -1e30f, m5 = -1e30f, m6 = -1e30f, m7 = -1e30f;
#pragma unroll 4
    for (int k = 0; k < KNN; ++k) {
        uint4 au = *(const uint4*)(src + (size_t)k * 128);
        float v0 = lrelu(fmaf(bf2f(au.x & 0xffff), sv0.x, tv0.x));
        float v1 = lrelu(fmaf(bf2f(au.x >> 16),    sv0.y, tv0.y));
        float v2 = lrelu(fmaf(bf2f(au.y & 0xffff), sv0.z, tv0.z));
        float v3 = lrelu(fmaf(bf2f(au.y >> 16),    sv0.w, tv0.w));
        float v4 = lrelu(fmaf(bf2f(au.z & 0xffff), sv1.x, tv1.x));
        float v5 = lrelu(fmaf(bf2f(au.z >> 16),    sv1.y, tv1.y));
        float v6 = lrelu(fmaf(bf2f(au.w & 0xffff), sv1.z, tv1.z));
        float v7 = lrelu(fmaf(bf2f(au.w >> 16),    sv1.w, tv1.w));
        half8 hv;
        hv[0] = (_Float16)v0; hv[1] = (_Float16)v1;
        hv[2] = (_Float16)v2; hv[3] = (_Float16)v3;
        hv[4] = (_Float16)v4; hv[5] = (_Float16)v5;
        hv[6] = (_Float16)v6; hv[7] = (_Float16)v7;
        *(half8*)(dst + (size_t)k * 128) = hv;
        m0 = fmaxf(m0, v0); m1 = fmaxf(m1, v1);
        m2 = fmaxf(m2, v2); m3 = fmaxf(m3, v3);
        m4 = fmaxf(m4, v4); m5 = fmaxf(m5, v5);
        m6 = fmaxf(m6, v6); m7 = fmaxf(m7, v7);
    }
    half8 hm;
    hm[0] = (_Float16)m0; hm[1] = (_Float16)m1;
    hm[2] = (_Float16)m2; hm[3] = (_Float16)m3;
    hm[4] = (_Float16)m4; hm[5] = (_Float16)m5;
    hm[6] = (_Float16)m6; hm[7] = (_Float16)m7;
    *(half8*)(c3 + (size_t)bn * 128 + c0) = hm;
}

// ---------------------------------------------------------------------------
// stats4: stage-4 stats via wide tile 128x256 (acc 2x16), copy staging both
// operands (y3a f16, W4h f16). A read ONCE (no col-split re-read).
// ---------------------------------------------------------------------------
__global__ __launch_bounds__(256, 2) void stats4_kernel(const _Float16* __restrict__ A,
                                                        const _Float16* __restrict__ Bh,
                                                        float* __restrict__ st)
{
    const int K = 128;
    __shared__ _Float16 Asm[128][LDA];     // 10 KB
    __shared__ _Float16 Bsm[256][LDA];     // 20 KB
    __shared__ float colsum[256], colsq[256];
    int t = threadIdx.x;
    int lane = t & 63, w = t >> 6;
    int quad = lane >> 4, l16 = lane & 15;
    size_t row0 = (size_t)blockIdx.x * 128;
    colsum[t] = 0.f; colsq[t] = 0.f;
    floatx4 acc[2][16];
#pragma unroll
    for (int mt = 0; mt < 2; ++mt)
#pragma unroll
        for (int nt = 0; nt < 16; ++nt)
            acc[mt][nt] = (floatx4){0.f, 0.f, 0.f, 0.f};

    for (int k0 = 0; k0 < K; k0 += 32) {
#pragma unroll
        for (int it = 0; it < 2; ++it) {           // A: 128x32 f16 copy
            int i = t + it * 256;
            int r = i >> 2, ko = (i & 3) * 8;
            *(uint4*)&Asm[r][ko] = *(const uint4*)(A + (row0 + r) * K + k0 + ko);
        }
#pragma unroll
        for (int it = 0; it < 4; ++it) {           // B: 256x32 f16 copy
            int i = t + it * 256;
            int n = i >> 2, seg = (i & 3) * 8;
            *(uint4*)&Bsm[n][seg] = *(const uint4*)(Bh + (size_t)n * K + k0 + seg);
        }
        __syncthreads();
        half8 af[2];
#pragma unroll
        for (int mt = 0; mt < 2; ++mt)
            af[mt] = *(const half8*)&Asm[w * 32 + mt * 16 + l16][quad * 8];
#pragma unroll
        for (int ng = 0; ng < 4; ++ng) {
            half8 bf[4];
#pragma unroll
            for (int j = 0; j < 4; ++j)
                bf[j] = *(const half8*)&Bsm[(ng * 4 + j) * 16 + l16][quad * 8];
#pragma unroll
            for (int mt = 0; mt < 2; ++mt)
#pragma unroll
                for (int j = 0; j < 4; ++j)
                    acc[mt][ng * 4 + j] = __builtin_amdgcn_mfma_f32_16x16x32_f16(
                        af[mt], bf[j], acc[mt][ng * 4 + j], 0, 0, 0);
        }
        __syncthreads();
    }
#pragma unroll
    for (int nt = 0; nt < 16; ++nt) {
        float s = 0.f, q = 0.f;
#pragma unroll
        for (int mt = 0; mt < 2; ++mt)
#pragma unroll
            for (int r = 0; r < 4; ++r) {
                float v = acc[mt][nt][r];
                s += v; q += v * v;
            }
        s += __shfl_xor(s, 16); q += __shfl_xor(q, 16);
        s += __shfl_xor(s, 32); q += __shfl_xor(q, 32);
        if (quad == 0) {
            atomicAdd(&colsum[nt * 16 + l16], s);
            atomicAdd(&colsq[nt * 16 + l16], q);
        }
    }
    __syncthreads();
    int bucket = blockIdx.x & 63;
    atomicAdd(&st[(size_t)bucket * 512 + t], colsum[t]);
    atomicAdd(&st[(size_t)bucket * 512 + 256 + t], colsq[t]);
}

// ---------------------------------------------------------------------------
// MFMA GEMM (s2/s3): act-staging path, 128x64 tile, XCD swizzle.
// ---------------------------------------------------------------------------
__global__ __launch_bounds__(256) void gemm_mfma_bn(const bf16_t* __restrict__ A,
                                                    const float* __restrict__ W,
                                                    const float* __restrict__ sIn,
                                                    const float* __restrict__ tIn,
                                                    bf16_t* __restrict__ Y,
                                                    float* __restrict__ st,
                                                    int K, int Nout, int log2ncol)
{
    __shared__ _Float16 Asm[128][LDA];
    __shared__ _Float16 Bsm[64][LDA];
    __shared__ float colsum[64], colsq[64];
    int t = threadIdx.x;
    int lane = t & 63, w = t >> 6;
    int quad = lane >> 4, l16 = lane & 15;
    int p = blockIdx.x;
    int q = p >> 3;
    int c = q & ((1 << log2ncol) - 1);
    int rb = (p & 7) + 8 * (q >> log2ncol);    // row-block
    size_t row0 = (size_t)rb * 128;
    int col0 = c * 64;
    if (t < 64) { colsum[t] = 0.f; colsq[t] = 0.f; }
    floatx4 acc[2][4];
#pragma unroll
    for (int mt = 0; mt < 2; ++mt)
#pragma unroll
        for (int nt = 0; nt < 4; ++nt)
            acc[mt][nt] = (floatx4){0.f, 0.f, 0.f, 0.f};

    for (int k0 = 0; k0 < K; k0 += 32) {
#pragma unroll
        for (int it = 0; it < 2; ++it) {           // A: 128x32 -> f16
            int i = t + it * 256;
            int r = i >> 2, ko = (i & 3) * 8;
            uint4 au = *(const uint4*)(A + (row0 + r) * K + k0 + ko);
            float4 sv0 = *(const float4*)(sIn + k0 + ko);
            float4 sv1 = *(const float4*)(sIn + k0 + ko + 4);
            float4 tv0 = *(const float4*)(tIn + k0 + ko);
            float4 tv1 = *(const float4*)(tIn + k0 + ko + 4);
            half8 hv;
            hv[0] = (_Float16)lrelu(fmaf(bf2f(au.x & 0xffff), sv0.x, tv0.x));
            hv[1] = (_Float16)lrelu(fmaf(bf2f(au.x >> 16),    sv0.y, tv0.y));
            hv[2] = (_Float16)lrelu(fmaf(bf2f(au.y & 0xffff), sv0.z, tv0.z));
            hv[3] = (_Float16)lrelu(fmaf(bf2f(au.y >> 16),    sv0.w, tv0.w));
            hv[4] = (_Float16)lrelu(fmaf(bf2f(au.z & 0xffff), sv1.x, tv1.x));
            hv[5] = (_Float16)lrelu(fmaf(bf2f(au.z >> 16),    sv1.y, tv1.y));
            hv[6] = (_Float16)lrelu(fmaf(bf2f(au.w & 0xffff), sv1.z, tv1.z));
            hv[7] = (_Float16)lrelu(fmaf(bf2f(au.w >> 16),    sv1.w, tv1.w));
            *(half8*)&Asm[r][ko] = hv;
        }
#pragma unroll
        for (int it = 0; it < 2; ++it) {           // B: 64x32 fp32 -> f16
            int i = t + it * 256;
            int n = i >> 3, seg = (i & 7) * 4;
            float4 bv = *(const float4*)(W + (size_t)(col0 + n) * K + k0 + seg);
            half4v h;
            h[0] = (_Float16)bv.x; h[1] = (_Float16)bv.y;
            h[2] = (_Float16)bv.z; h[3] = (_Float16)bv.w;
            *(half4v*)&Bsm[n][seg] = h;
        }
        __syncthreads();
        half8 af[2], bf[4];
#pragma unroll
        for (int mt = 0; mt < 2; ++mt)
            af[mt] = *(const half8*)&Asm[w * 32 + mt * 16 + l16][quad * 8];
#pragma unroll
        for (int nt = 0; nt < 4; ++nt)
            bf[nt] = *(const half8*)&Bsm[nt * 16 + l16][quad * 8];
#pragma unroll
        for (int mt = 0; mt < 2; ++mt)
#pragma unroll
            for (int nt = 0; nt < 4; ++nt)
                acc[mt][nt] = __builtin_amdgcn_mfma_f32_16x16x32_f16(
                    af[mt], bf[nt], acc[mt][nt], 0, 0, 0);
        __syncthreads();
    }
#pragma unroll
    for (int mt = 0; mt < 2; ++mt)
#pragma unroll
        for (int nt = 0; nt < 4; ++nt)
#pragma unroll
            for (int r = 0; r < 4; ++r) {
                size_t row = row0 + w * 32 + mt * 16 + quad * 4 + r;
                Y[row * Nout + col0 + nt * 16 + l16] = f2bf(acc[mt][nt][r]);
            }
#pragma unroll
    for (int nt = 0; nt < 4; ++nt) {
        float s = 0.f, q2 = 0.f;
#pragma unroll
        for (int mt = 0; mt < 2; ++mt)
#pragma unroll
            for (int r = 0; r < 4; ++r) {
                float v = acc[mt][nt][r];
                s += v; q2 += v * v;
            }
        s += __shfl_xor(s, 16); q2 += __shfl_xor(q2, 16);
        s += __shfl_xor(s, 32); q2 += __shfl_xor(q2, 32);
        if (quad == 0) {
            atomicAdd(&colsum[nt * 16 + l16], s);
            atomicAdd(&colsq[nt * 16 + l16], q2);
        }
    }
    __syncthreads();
    int bucket = rb & 63;
    if (t < 64) {
        atomicAdd(&st[(size_t)bucket * 2 * Nout + col0 + t], colsum[t]);
        atomicAdd(&st[(size_t)bucket * 2 * Nout + Nout + col0 + t], colsq[t]);
    }
}

// ---------------------------------------------------------------------------
// Stage-4 fused pass 2 (MFMA): LDS union (43.5 KB -> 3 blocks/CU), XCD
// swizzle. Writes f16 slab4.
// ---------------------------------------------------------------------------
__global__ __launch_bounds__(256) void gemm4_mfma(const _Float16* __restrict__ A,
                                                  const float* __restrict__ W,
                                                  const float* __restrict__ s4,
                                                  const float* __restrict__ t4,
                                                  _Float16* __restrict__ slab4)
{
    const int K = 128;
    __shared__ __align__(16) unsigned char smem[320 * 68 * 2];   // 43520 B
    _Float16 (*Asm)[LDA] = (_Float16 (*)[LDA])smem;              // 25600 B
    _Float16 (*Bsm)[LDA] = (_Float16 (*)[LDA])(smem + 320 * LDA * 2); // +5120
    _Float16 (*tile)[68] = (_Float16 (*)[68])smem;               // post-loop
    int t = threadIdx.x;
    int lane = t & 63, w = t >> 6;
    int quad = lane >> 4, l16 = lane & 15;
    int p = blockIdx.x;
    int q = p >> 3;
    int c = q & 3;
    int rb = (p & 7) + 8 * (q >> 2);           // row-block 0..1023
    size_t row0 = (size_t)rb * 320;
    int col0 = c * 64;
    floatx4 acc[5][4];
#pragma unroll
    for (int mt = 0; mt < 5; ++mt)
#pragma unroll
        for (int nt = 0; nt < 4; ++nt)
            acc[mt][nt] = (floatx4){0.f, 0.f, 0.f, 0.f};

    for (int k0 = 0; k0 < K; k0 += 32) {
#pragma unroll
        for (int it = 0; it < 5; ++it) {           // A: 320x32 plain f16 copy
            int i = t + it * 256;
            int r = i >> 2, ko = (i & 3) * 8;
            uint4 au = *(const uint4*)(A + (row0 + r) * K + k0 + ko);
            *(uint4*)&Asm[r][ko] = au;
        }
#pragma unroll
        for (int it = 0; it < 2; ++it) {           // B: 64x32
            int i = t + it * 256;
            int n = i >> 3, seg = (i & 7) * 4;
            float4 bv = *(const float4*)(W + (size_t)(col0 + n) * K + k0 + seg);
            half4v h;
            h[0] = (_Float16)bv.x; h[1] = (_Float16)bv.y;
            h[2] = (_Float16)bv.z; h[3] = (_Float16)bv.w;
            *(half4v*)&Bsm[n][seg] = h;
        }
        __syncthreads();
        half8 af[5], bf[4];
#pragma unroll
        for (int mt = 0; mt < 5; ++mt)
            af[mt] = *(const half8*)&Asm[w * 80 + mt * 16 + l16][quad * 8];
#pragma unroll
        for (int nt = 0; nt < 4; ++nt)
            bf[nt] = *(const half8*)&Bsm[nt * 16 + l16][quad * 8];
#pragma unroll
        for (int mt = 0; mt < 5; ++mt)
#pragma unroll
            for (int nt = 0; nt < 4; ++nt)
                acc[mt][nt] = __builtin_amdgcn_mfma_f32_16x16x32_f16(
                    af[mt], bf[nt], acc[mt][nt], 0, 0, 0);
        __syncthreads();                           // also guards smem reuse
    }
    float s4c[4], t4c[4];
#pragma unroll
    for (int nt = 0; nt < 4; ++nt) {
        s4c[nt] = s4[col0 + nt * 16 + l16];
        t4c[nt] = t4[col0 + nt * 16 + l16];
    }
#pragma unroll
    for (int mt = 0; mt < 5; ++mt)
#pragma unroll
        for (int nt = 0; nt < 4; ++nt)
#pragma unroll
            for (int r = 0; r < 4; ++r) {
                int rl = w * 80 + mt * 16 + quad * 4 + r;
                tile[rl][nt * 16 + l16] =
                    (_Float16)lrelu(fmaf(acc[mt][nt][r], s4c[nt], t4c[nt]));
            }
    __syncthreads();
    int col = t & 63;
#pragma unroll
    for (int g = 0; g < 4; ++g) {
        int pt = (t >> 6) * 4 + g;                 // 0..15
        float m = -1e30f;
#pragma unroll
        for (int k = 0; k < KNN; ++k)
            m = fmaxf(m, (float)tile[pt * KNN + k][col]);
        slab4[((size_t)rb * 16 + pt) * 256 + col0 + col] = (_Float16)m;
    }
}

// ---------------------------------------------------------------------------
// Final GEMM wide: y5[M5,1024] = cat[M5,512]*W5h^T, tile 128x256 (acc 2x16),
// pure-copy staging (f16 slabs + pre-converted W5h). Stats epilogue + y5 out.
// ---------------------------------------------------------------------------
__global__ __launch_bounds__(256, 2) void gemm5_wide(const _Float16* __restrict__ c1,
                                                     const _Float16* __restrict__ c2,
                                                     const _Float16* __restrict__ c3,
                                                     const _Float16* __restrict__ c4,
                                                     const _Float16* __restrict__ W5h,
                                                     float* __restrict__ Y,
                                                     float* __restrict__ st)
{
    const int K = 512, Nout = 1024;
    __shared__ _Float16 Asm[128][LDA];     // 10 KB
    __shared__ _Float16 Bsm[256][LDA];     // 20 KB
    __shared__ float colsum[256], colsq[256];
    int t = threadIdx.x;
    int lane = t & 63, w = t >> 6;
    int quad = lane >> 4, l16 = lane & 15;
    size_t row0 = (size_t)blockIdx.y * 128;
    int col0 = blockIdx.x * 256;
    colsum[t] = 0.f; colsq[t] = 0.f;
    floatx4 acc[2][16];
#pragma unroll
    for (int mt = 0; mt < 2; ++mt)
#pragma unroll
        for (int nt = 0; nt < 16; ++nt)
            acc[mt][nt] = (floatx4){0.f, 0.f, 0.f, 0.f};

    for (int k0 = 0; k0 < K; k0 += 32) {
        const _Float16* base; int stride, off;
        if (k0 < 64)       { base = c1; stride = 64;  off = 0; }
        else if (k0 < 128) { base = c2; stride = 64;  off = 64; }
        else if (k0 < 256) { base = c3; stride = 128; off = 128; }
        else               { base = c4; stride = 256; off = 256; }
#pragma unroll
        for (int it = 0; it < 2; ++it) {           // A: 128x32 f16 copy
            int i = t + it * 256;
            int r = i >> 2, ko = (i & 3) * 8;
            *(uint4*)&Asm[r][ko] = *(const uint4*)(base
                + (size_t)(row0 + r) * stride + (k0 - off) + ko);
        }
#pragma unroll
        for (int it = 0; it < 4; ++it) {           // B: 256x32 f16 copy
            int i = t + it * 256;
            int n = i >> 2, seg = (i & 3) * 8;
            *(uint4*)&Bsm[n][seg] = *(const uint4*)(W5h
                + (size_t)(col0 + n) * K + k0 + seg);
        }
        __syncthreads();
        half8 af[2];
#pragma unroll
        for (int mt = 0; mt < 2; ++mt)
            af[mt] = *(const half8*)&Asm[w * 32 + mt * 16 + l16][quad * 8];
#pragma unroll
        for (int ng = 0; ng < 4; ++ng) {
            half8 bf[4];
#pragma unroll
            for (int j = 0; j < 4; ++j)
                bf[j] = *(const half8*)&Bsm[(ng * 4 + j) * 16 + l16][quad * 8];
#pragma unroll
            for (int mt = 0; mt < 2; ++mt)
#pragma unroll
                for (int j = 0; j < 4; ++j)
                    acc[mt][ng * 4 + j] = __builtin_amdgcn_mfma_f32_16x16x32_f16(
                        af[mt], bf[j], acc[mt][ng * 4 + j], 0, 0, 0);
        }
        __syncthreads();
    }
#pragma unroll
    for (int mt = 0; mt < 2; ++mt)
#pragma unroll
        for (int nt = 0; nt < 16; ++nt)
#pragma unroll
            for (int r = 0; r < 4; ++r) {
                size_t row = row0 + w * 32 + mt * 16 + quad * 4 + r;
                Y[row * Nout + col0 + nt * 16 + l16] = acc[mt][nt][r];
            }
#pragma unroll
    for (int nt = 0; nt < 16; ++nt) {
        float s = 0.f, q = 0.f;
#pragma unroll
        for (int mt = 0; mt < 2; ++mt)
#pragma unroll
            for (int r = 0; r < 4; ++r) {
                float v = acc[mt][nt][r];
                s += v; q += v * v;
            }
        s += __shfl_xor(s, 16); q += __shfl_xor(q, 16);
        s += __shfl_xor(s, 32); q += __shfl_xor(q, 32);
        if (quad == 0) {
            atomicAdd(&colsum[nt * 16 + l16], s);
            atomicAdd(&colsq[nt * 16 + l16], q);
        }
    }
    __syncthreads();
    int bucket = blockIdx.y & 63;
    atomicAdd(&st[(size_t)bucket * 2 * Nout + col0 + t], colsum[t]);
    atomicAdd(&st[(size_t)bucket * 2 * Nout + Nout + col0 + t], colsq[t]);
}

// ---------------------------------------------------------------------------
__global__ void finalize_kernel(const float* __restrict__ st,
                                const float* __restrict__ g,
                                const float* __restrict__ bb,
                                float* __restrict__ s, float* __restrict__ tt,
                                int C, float invM)
{
    int c = blockIdx.x * blockDim.x + threadIdx.x;
    if (c >= C) return;
    float sum = 0.f, sq = 0.f;
    for (int bk = 0; bk < 64; ++bk) {
        sum += st[(size_t)bk * 2 * C + c];
        sq  += st[(size_t)bk * 2 * C + C + c];
    }
    float mu  = sum * invM;
    float var = sq * invM - mu * mu;
    float sc  = g[c] * rsqrtf(var + EPSBN);
    s[c]  = sc;
    tt[c] = bb[c] - mu * sc;
}

// ---------------------------------------------------------------------------
__global__ __launch_bounds__(256) void maxk_kernel(const bf16_t* __restrict__ Y,
                                                   const float* __restrict__ s,
                                                   const float* __restrict__ tt,
                                                   _Float16* __restrict__ slab,
                                                   int C, int logC)
{
    int gid = blockIdx.x * 256 + threadIdx.x;
    int c = gid & (C - 1);
    int bn = gid >> logC;
    float sc = s[c], tc = tt[c];
    const bf16_t* p = Y + (size_t)bn * KNN * C + c;
    float m = -1e30f;
#pragma unroll
    for (int kk = 0; kk < KNN; ++kk) {
        float v = fmaf(bf2f(p[(size_t)kk * C]), sc, tc);
        m = fmaxf(m, lrelu(v));
    }
    slab[(size_t)bn * C + c] = (_Float16)m;
}

// ---------------------------------------------------------------------------
__global__ __launch_bounds__(256) void out_kernel(const float* __restrict__ y5,
                                                  const float* __restrict__ s,
                                                  const float* __restrict__ tt,
                                                  float* __restrict__ out)
{
    __shared__ float tile[32][65];
    int t = threadIdx.x;
    int b = blockIdx.z;
    int o0 = blockIdx.y * 32;
    int n0 = blockIdx.x * 64;
#pragma unroll
    for (int p = 0; p < 8; ++p) {
        int ol = t & 31, nl = (t >> 5) + 8 * p;
        tile[ol][nl] = y5[((size_t)b * NPTS + n0 + nl) * 1024 + o0 + ol];
    }
    __syncthreads();
#pragma unroll
    for (int p = 0; p < 8; ++p) {
        int nl = t & 63, ol = (t >> 6) + 4 * p;
        float v = fmaf(tile[ol][nl], s[o0 + ol], tt[o0 + ol]);
        out[(size_t)b * 1024 * NPTS + (size_t)(o0 + ol) * NPTS + n0 + nl] = lrelu(v);
    }
}

// ---------------------------------------------------------------------------
extern "C" void kernel_launch(void* const* d_in, const int* in_sizes, int n_in,
                              void* d_out, int out_size, void* d_ws, size_t ws_size,
                              hipStream_t stream)
{
    const float* x  = (const float*)d_in[0];
    const float* W1 = (const float*)d_in[1];
    const float* g1 = (const float*)d_in[2];  const float* b1 = (const float*)d_in[3];
    const float* W2 = (const float*)d_in[4];
    const float* g2 = (const float*)d_in[5];  const float* b2 = (const float*)d_in[6];
    const float* W3 = (const float*)d_in[7];
    const float* g3 = (const float*)d_in[8];  const float* b3 = (const float*)d_in[9];
    const float* W4 = (const float*)d_in[10];
    const float* g4 = (const float*)d_in[11]; const float* b4 = (const float*)d_in[12];
    const float* W5 = (const float*)d_in[13];
    const float* g5 = (const float*)d_in[14]; const float* b5 = (const float*)d_in[15];
    float* out = (float*)d_out;

    // -------- workspace layout (~195 MB total) --------
    char* p = (char*)d_ws;
    int* idx = (int*)p;                 p += (size_t)M1 * 4;                 // 1.3 MB
    bf16_t* y1 = (bf16_t*)p;
    float*  y5 = (float*)p;
    _Float16* y3a = (_Float16*)p;       p += (size_t)M1 * 64 * 2;           // arena A
    bf16_t* y2 = (bf16_t*)p;            p += (size_t)M1 * 64 * 2;
    bf16_t* y3 = (bf16_t*)p;            p += (size_t)M1 * 128 * 2;
    _Float16* c1 = (_Float16*)p;        p += (size_t)M5 * 64 * 4;           // f16 slabs
    _Float16* c2 = (_Float16*)p;        p += (size_t)M5 * 64 * 4;
    _Float16* c3 = (_Float16*)p;        p += (size_t)M5 * 128 * 4;
    _Float16* c4 = (_Float16*)p;        p += (size_t)M5 * 256 * 4;
    float* st1 = (float*)p;             p += 64 * 2 * 64 * 4;
    float* st2 = (float*)p;             p += 64 * 2 * 64 * 4;
    float* st3 = (float*)p;             p += 64 * 2 * 128 * 4;
    float* st4 = (float*)p;             p += 64 * 2 * 256 * 4;
    float* st5 = (float*)p;             p += 64 * 2 * 1024 * 4;
    _Float16* W4h = (_Float16*)p;       p += 256 * 128 * 2;                 // 64 KB
    _Float16* W5h = (_Float16*)p;       p += (size_t)1024 * 512 * 2;        // 1 MB
    float* s1 = (float*)p; p += 64 * 4;   float* t1 = (float*)p; p += 64 * 4;
    float* s2 = (float*)p; p += 64 * 4;   float* t2 = (float*)p; p += 64 * 4;
    float* s3 = (float*)p; p += 128 * 4;  float* t3 = (float*)p; p += 128 * 4;
    float* s4 = (float*)p; p += 256 * 4;  float* t4 = (float*)p; p += 256 * 4;
    float* s5 = (float*)p; p += 1024 * 4; float* t5 = (float*)p; p += 1024 * 4;
    // y3a (M1*128 fp16 = 84 MB) aliases arena A (y1) + y2: y1/y2 are dead
    // before stage 4; y5 overwrites the arena only after gemm4 completes.

    size_t statsBytes = (size_t)(64 * 2 * (64 + 64 + 128 + 256 + 1024)) * 4;
    hipMemsetAsync(st1, 0, statsBytes, stream);

    const float invM14 = 1.0f / (float)M1;
    const float invM5  = 1.0f / (float)M5;

    // weight pre-conversion (f32 -> f16, same rounding as old in-staging cvt)
    cvt_kernel<<<(256 * 128) / 2048, 256, 0, stream>>>(W4, W4h);
    cvt_kernel<<<(1024 * 512) / 2048, 256, 0, stream>>>(W5, W5h);

    knn_kernel<<<M5 / 16, 512, 0, stream>>>(x, idx);

    // stage 1
    conv1_kernel<<<M1 / 64, 256, 0, stream>>>(x, idx, W1, y1, st1);
    finalize_kernel<<<1, 256, 0, stream>>>(st1, g1, b1, s1, t1, 64, invM14);
    maxk_kernel<<<(M5 * 64) / 256, 256, 0, stream>>>(y1, s1, t1, c1, 64, 6);

    // stage 2 (ncol=1 -> swizzle is identity)
    gemm_mfma_bn<<<M1 / 128, 256, 0, stream>>>(y1, W2, s1, t1, y2, st2, 64, 64, 0);
    finalize_kernel<<<1, 256, 0, stream>>>(st2, g2, b2, s2, t2, 64, invM14);
    maxk_kernel<<<(M5 * 64) / 256, 256, 0, stream>>>(y2, s2, t2, c2, 64, 6);

    // stage 3 (ncol=2, XCD-swizzled)
    gemm_mfma_bn<<<(M1 / 128) * 2, 256, 0, stream>>>(y2, W3, s2, t2, y3, st3, 64, 128, 1);
    finalize_kernel<<<1, 256, 0, stream>>>(st3, g3, b3, s3, t3, 128, invM14);

    // stage 4: fused act+maxk -> wide stats -> fused BN+max GEMM
    actmax3_kernel<<<M5 / 16, 256, 0, stream>>>(y3, s3, t3, y3a, c3);
    stats4_kernel<<<M1 / 128, 256, 0, stream>>>(y3a, W4h, st4);
    finalize_kernel<<<1, 256, 0, stream>>>(st4, g4, b4, s4, t4, 256, invM14);
    gemm4_mfma<<<(M1 / 320) * 4, 256, 0, stream>>>(y3a, W4, s4, t4, c4);

    // stage 5 (wide tile, f16 everything)
    gemm5_wide<<<dim3(4, M5 / 128), 256, 0, stream>>>(c1, c2, c3, c4, W5h, y5, st5);
    finalize_kernel<<<4, 256, 0, stream>>>(st5, g5, b5, s5, t5, 1024, invM5);

    out_kernel<<<dim3(NPTS / 64, 1024 / 32, BATCH), 256, 0, stream>>>(y5, s5, t5, out);
}